// Round 3
// baseline (552.689 us; speedup 1.0000x reference)
//
#include <hip/hip_runtime.h>

#define B_ 1024
#define N_ 256
#define C_ 128
#define L_ 4

typedef __bf16 bf16x8 __attribute__((ext_vector_type(8)));
typedef float f32x4 __attribute__((ext_vector_type(4)));

__device__ __forceinline__ float b2f(unsigned short u) {
    union { unsigned int i; float f; } v; v.i = ((unsigned int)u) << 16; return v.f;
}
__device__ __forceinline__ unsigned short f2b(float f) {
    union { float f; unsigned int i; } v; v.f = f;
    unsigned int u = v.i;
    u = (u + 0x7FFFu + ((u >> 16) & 1u)) >> 16;
    return (unsigned short)u;
}

// ---------------------------------------------------------------------------
// Kernel 0: prep. wtp[br][mat][d][c] = W[mat][c][d] (mat0: W0-W2 folded), bf16.
// Also adj -> bf16 copy.
// ---------------------------------------------------------------------------
extern "C" __global__ __launch_bounds__(256) void k_prep(
    const float* __restrict__ Wt,
    const float* __restrict__ Wf,
    const float* __restrict__ adjf,
    unsigned short* __restrict__ wtp,
    unsigned short* __restrict__ adj_bs)
{
    int i = blockIdx.x * 256 + threadIdx.x;      // [0, 163840)
    if (i < 98304) {
        int br = i / 49152;
        int r  = i - br * 49152;
        int mat = r >> 14;
        int r2  = r & 16383;
        int d = r2 >> 7, c = r2 & 127;
        const float* S = br ? Wf : Wt;
        float v = S[mat * 16384 + c * 128 + d];
        if (mat == 0) v -= S[2 * 16384 + c * 128 + d];
        wtp[i] = f2b(v);
    } else {
        int j = i - 98304;                        // [0, 65536)
        adj_bs[j] = f2b(adjf[j]);
    }
}

// ---------------------------------------------------------------------------
// Kernel 1: latent attention. fused[b][l][c] (f32) = softmax(lat@concat^T/√C)@concat
// One block per batch. LDS: concat bf16 128KB (swizzled) + scores 8KB + lat 2KB.
// ---------------------------------------------------------------------------
extern "C" __global__ __launch_bounds__(256) void k_latent(
    const float* __restrict__ timep,
    const float* __restrict__ frep,
    const float* __restrict__ latents,
    float* __restrict__ fused_out)
{
    extern __shared__ char smem[];
    float* scr = (float*)(smem + 131072);             // [4][512]
    float* lat = (float*)(smem + 131072 + 8192);      // [4][128]
    const int t = threadIdx.x;
    const int b = blockIdx.x;
    const float4* tg = (const float4*)(timep + (size_t)b * (N_ * C_));  // 8192 each
    const float4* fg = (const float4*)(frep  + (size_t)b * (N_ * C_));
#pragma unroll
    for (int i = 0; i < 64; ++i) {
        int ch = i * 256 + t;                     // [0,16384)
        const float4* p = (ch < 8192) ? (tg + ch) : (fg + (ch - 8192));
        float4 u = *p;
        int row = ch >> 5, c4 = ch & 31;
        unsigned short o[4] __attribute__((aligned(8)));
        o[0] = f2b(u.x); o[1] = f2b(u.y); o[2] = f2b(u.z); o[3] = f2b(u.w);
        *(uint2*)(smem + row * 256 + ((c4 * 8) ^ ((row & 7) << 4))) = *(const uint2*)o;
    }
    for (int i = t; i < L_ * C_; i += 256) lat[i] = latents[i];
    __syncthreads();

    const float isc = 0.0883883476483184f;   // 1/sqrt(128)
    for (int jj = t; jj < 2 * N_; jj += 256) {
        float s0 = 0, s1 = 0, s2 = 0, s3 = 0;
#pragma unroll
        for (int ci = 0; ci < 16; ++ci) {
            uint4 u = *(const uint4*)(smem + jj * 256 + ((ci * 16) ^ ((jj & 7) << 4)));
            const unsigned short* xb = (const unsigned short*)&u;
#pragma unroll
            for (int i = 0; i < 8; ++i) {
                float xv = b2f(xb[i]); int c = ci * 8 + i;
                s0 += xv * lat[c];           s1 += xv * lat[C_ + c];
                s2 += xv * lat[2 * C_ + c];  s3 += xv * lat[3 * C_ + c];
            }
        }
        scr[jj] = s0 * isc; scr[512 + jj] = s1 * isc;
        scr[1024 + jj] = s2 * isc; scr[1536 + jj] = s3 * isc;
    }
    __syncthreads();

    const int w = t >> 6, lane = t & 63;
    {   // wave w owns latent row l=w: softmax over 512
        float v[8]; float m = -1e30f;
#pragma unroll
        for (int i = 0; i < 8; ++i) { v[i] = scr[w * 512 + lane * 8 + i]; m = fmaxf(m, v[i]); }
#pragma unroll
        for (int off = 32; off >= 1; off >>= 1) m = fmaxf(m, __shfl_xor(m, off));
        float s = 0;
#pragma unroll
        for (int i = 0; i < 8; ++i) { v[i] = __expf(v[i] - m); s += v[i]; }
#pragma unroll
        for (int off = 32; off >= 1; off >>= 1) s += __shfl_xor(s, off);
        float inv = 1.0f / s;
#pragma unroll
        for (int i = 0; i < 8; ++i) scr[w * 512 + lane * 8 + i] = v[i] * inv;
    }
    __syncthreads();
    {   // weighted sum: wave w owns l=w, lane owns channels 2*lane, 2*lane+1
        float f0 = 0.f, f1 = 0.f;
        for (int j = 0; j < 512; ++j) {
            float p = scr[w * 512 + j];
            unsigned int pr = *(const unsigned int*)(smem + j * 256 + ((lane * 4) ^ ((j & 7) << 4)));
            f0 += p * b2f((unsigned short)(pr & 0xFFFFu));
            f1 += p * b2f((unsigned short)(pr >> 16));
        }
        float* fo = fused_out + ((size_t)b * L_ + w) * C_ + lane * 2;
        fo[0] = f0; fo[1] = f1;
    }
}

// ---------------------------------------------------------------------------
// Kernel 2: per (batch, branch): cross-attn + residual + chebyshev conv.
// LDS regions: A = bytes [0,64K): xs -> ts
//              B = bytes [64K,128K): xsT -> vT      fused_s at 128K (2KB)
// All LDS tiles XOR-swizzled: byte_in_row ^= (row&7)<<4
// Output written directly as f32.
// ---------------------------------------------------------------------------
extern "C" __global__ __launch_bounds__(512, 1) void k_main(
    const float* __restrict__ timep,
    const float* __restrict__ frep,
    const unsigned short* __restrict__ adj,       // bf16 copy in ws
    const float* __restrict__ fused_ws,
    const float* __restrict__ scale_tp,
    const float* __restrict__ scale_fp,
    const unsigned short* __restrict__ wtp,
    const float* __restrict__ btp,
    const float* __restrict__ bfp,
    float* __restrict__ outp)
{
    extern __shared__ char smem[];
    float* fused_s = (float*)(smem + 131072);
    const int t  = threadIdx.x;
    const int b  = blockIdx.x;
    const int br = blockIdx.y;
    const float* xg = (br ? frep : timep) + (size_t)b * (N_ * C_);
    const unsigned short* wt = wtp + br * (3 * C_ * C_);
    const float* bias = br ? bfp : btp;
    float* og = outp + (size_t)br * B_ * N_ * C_ + (size_t)b * (N_ * C_);
    const float scale = (br ? scale_fp : scale_tp)[0];

    fused_s[t] = fused_ws[(size_t)b * (L_ * C_) + t];
    __syncthreads();

    // ---- P1: x' = x + scale * softmax(x·fused/√C) @ fused; write xs + xsT
    {
        const int n = t >> 1, h = t & 1;
        float xv[64];
        const float4* xr = (const float4*)(xg + n * C_ + h * 64);
#pragma unroll
        for (int i4 = 0; i4 < 16; ++i4) {
            float4 u = xr[i4];
            xv[i4 * 4 + 0] = u.x; xv[i4 * 4 + 1] = u.y;
            xv[i4 * 4 + 2] = u.z; xv[i4 * 4 + 3] = u.w;
        }
        float s0 = 0, s1 = 0, s2 = 0, s3 = 0;
#pragma unroll
        for (int k = 0; k < 64; ++k) {
            int c = h * 64 + k; float x = xv[k];
            s0 += x * fused_s[c];          s1 += x * fused_s[C_ + c];
            s2 += x * fused_s[2 * C_ + c]; s3 += x * fused_s[3 * C_ + c];
        }
        s0 += __shfl_xor(s0, 1); s1 += __shfl_xor(s1, 1);
        s2 += __shfl_xor(s2, 1); s3 += __shfl_xor(s3, 1);
        const float isc = 0.0883883476483184f;
        s0 *= isc; s1 *= isc; s2 *= isc; s3 *= isc;
        float m = fmaxf(fmaxf(s0, s1), fmaxf(s2, s3));
        float p0 = __expf(s0 - m), p1 = __expf(s1 - m), p2 = __expf(s2 - m), p3 = __expf(s3 - m);
        float inv = scale / (p0 + p1 + p2 + p3);
        p0 *= inv; p1 *= inv; p2 *= inv; p3 *= inv;
#pragma unroll
        for (int ci = 0; ci < 8; ++ci) {
            unsigned short ov[8] __attribute__((aligned(16)));
#pragma unroll
            for (int i = 0; i < 8; ++i) {
                int k = ci * 8 + i; int c = h * 64 + k;
                float v = xv[k] + p0 * fused_s[c] + p1 * fused_s[C_ + c]
                        + p2 * fused_s[2 * C_ + c] + p3 * fused_s[3 * C_ + c];
                unsigned short bv = f2b(v);
                ov[i] = bv;
                // xsT[c][n] (region B), row stride 512B
                *(unsigned short*)(smem + 65536 + c * 512 + ((n * 2) ^ ((c & 7) << 4))) = bv;
            }
            int chunk = h * 8 + ci;   // xs[n][*] (region A), row stride 256B
            *(uint4*)(smem + n * 256 + ((chunk * 16) ^ ((n & 7) << 4))) = *(const uint4*)ov;
        }
    }
    __syncthreads();

    const int w = t >> 6, lane = t & 63;
    const int wm = w >> 1, wn = w & 1;          // wave tile: rows [wm*64,+64), cols [wn*64,+64)
    const int lr = lane & 15, lq = lane >> 4;

    // ---- P2 init: acc = x' + bias  (D layout: row = base+lq*4+r, col = base+lr)
    f32x4 accy[16];
#pragma unroll
    for (int fn = 0; fn < 4; ++fn) {
        int col = wn * 64 + fn * 16 + lr;
        float bv = bias[col];
#pragma unroll
        for (int fm = 0; fm < 4; ++fm) {
            f32x4 a;
#pragma unroll
            for (int r = 0; r < 4; ++r) {
                int row = wm * 64 + fm * 16 + lq * 4 + r;
                a[r] = b2f(*(const unsigned short*)(smem + row * 256 + ((col * 2) ^ ((row & 7) << 4)))) + bv;
            }
            accy[fm * 4 + fn] = a;
        }
    }
    // ---- P2: acc += xs @ (W0-W2)   [K=128]
#pragma unroll
    for (int kk = 0; kk < 4; ++kk) {
        int kb = kk * 64 + lq * 16;
        bf16x8 afr[4], bfr[4];
#pragma unroll
        for (int fm = 0; fm < 4; ++fm) {
            int row = wm * 64 + fm * 16 + lr;
            afr[fm] = __builtin_bit_cast(bf16x8, *(const uint4*)(smem + row * 256 + (kb ^ ((row & 7) << 4))));
        }
#pragma unroll
        for (int fn = 0; fn < 4; ++fn) {
            int d = wn * 64 + fn * 16 + lr;
            bfr[fn] = __builtin_bit_cast(bf16x8, *(const uint4*)(wt + d * C_ + kk * 32 + lq * 8));
        }
#pragma unroll
        for (int fm = 0; fm < 4; ++fm)
#pragma unroll
            for (int fn = 0; fn < 4; ++fn)
                accy[fm * 4 + fn] = __builtin_amdgcn_mfma_f32_16x16x32_bf16(afr[fm], bfr[fn], accy[fm * 4 + fn], 0, 0, 0);
    }
    __syncthreads();

    // ---- P3: t1 = adj @ x'  (A-op from adj_bs, B-op from xsT) -> ts (region A)
    f32x4 acc2[16];
#pragma unroll
    for (int i = 0; i < 16; ++i) acc2[i] = f32x4{0.f, 0.f, 0.f, 0.f};
#pragma unroll
    for (int kk = 0; kk < 8; ++kk) {
        int kb = kk * 64 + lq * 16;
        bf16x8 afr[4], bfr[4];
#pragma unroll
        for (int fm = 0; fm < 4; ++fm) {
            int row = wm * 64 + fm * 16 + lr;
            afr[fm] = __builtin_bit_cast(bf16x8, *(const uint4*)(adj + row * N_ + kk * 32 + lq * 8));
        }
#pragma unroll
        for (int fn = 0; fn < 4; ++fn) {
            int cr = wn * 64 + fn * 16 + lr;
            bfr[fn] = __builtin_bit_cast(bf16x8, *(const uint4*)(smem + 65536 + cr * 512 + (kb ^ ((cr & 7) << 4))));
        }
#pragma unroll
        for (int fm = 0; fm < 4; ++fm)
#pragma unroll
            for (int fn = 0; fn < 4; ++fn)
                acc2[fm * 4 + fn] = __builtin_amdgcn_mfma_f32_16x16x32_bf16(afr[fm], bfr[fn], acc2[fm * 4 + fn], 0, 0, 0);
    }
#pragma unroll
    for (int fm = 0; fm < 4; ++fm)
#pragma unroll
        for (int fn = 0; fn < 4; ++fn) {
            int col = wn * 64 + fn * 16 + lr;
            f32x4 a = acc2[fm * 4 + fn];
#pragma unroll
            for (int r = 0; r < 4; ++r) {
                int row = wm * 64 + fm * 16 + lq * 4 + r;
                *(unsigned short*)(smem + row * 256 + ((col * 2) ^ ((row & 7) << 4))) = f2b(a[r]);
            }
        }
    __syncthreads();

    // ---- P4: acc += ts @ W1   [K=128]
    const unsigned short* w1 = wt + C_ * C_;
#pragma unroll
    for (int kk = 0; kk < 4; ++kk) {
        int kb = kk * 64 + lq * 16;
        bf16x8 afr[4], bfr[4];
#pragma unroll
        for (int fm = 0; fm < 4; ++fm) {
            int row = wm * 64 + fm * 16 + lr;
            afr[fm] = __builtin_bit_cast(bf16x8, *(const uint4*)(smem + row * 256 + (kb ^ ((row & 7) << 4))));
        }
#pragma unroll
        for (int fn = 0; fn < 4; ++fn) {
            int d = wn * 64 + fn * 16 + lr;
            bfr[fn] = __builtin_bit_cast(bf16x8, *(const uint4*)(w1 + d * C_ + kk * 32 + lq * 8));
        }
#pragma unroll
        for (int fm = 0; fm < 4; ++fm)
#pragma unroll
            for (int fn = 0; fn < 4; ++fn)
                accy[fm * 4 + fn] = __builtin_amdgcn_mfma_f32_16x16x32_bf16(afr[fm], bfr[fn], accy[fm * 4 + fn], 0, 0, 0);
    }

    // ---- P5: v = 2*(ts @ W2)  [K=128], store TRANSPOSED vT[d][m] (region B)
    const unsigned short* w2 = wt + 2 * C_ * C_;
#pragma unroll
    for (int i = 0; i < 16; ++i) acc2[i] = f32x4{0.f, 0.f, 0.f, 0.f};
#pragma unroll
    for (int kk = 0; kk < 4; ++kk) {
        int kb = kk * 64 + lq * 16;
        bf16x8 afr[4], bfr[4];
#pragma unroll
        for (int fm = 0; fm < 4; ++fm) {
            int row = wm * 64 + fm * 16 + lr;
            afr[fm] = __builtin_bit_cast(bf16x8, *(const uint4*)(smem + row * 256 + (kb ^ ((row & 7) << 4))));
        }
#pragma unroll
        for (int fn = 0; fn < 4; ++fn) {
            int d = wn * 64 + fn * 16 + lr;
            bfr[fn] = __builtin_bit_cast(bf16x8, *(const uint4*)(w2 + d * C_ + kk * 32 + lq * 8));
        }
#pragma unroll
        for (int fm = 0; fm < 4; ++fm)
#pragma unroll
            for (int fn = 0; fn < 4; ++fn)
                acc2[fm * 4 + fn] = __builtin_amdgcn_mfma_f32_16x16x32_bf16(afr[fm], bfr[fn], acc2[fm * 4 + fn], 0, 0, 0);
    }
    __syncthreads();   // all xsT readers (P3) done before vT overwrite
#pragma unroll
    for (int fm = 0; fm < 4; ++fm)
#pragma unroll
        for (int fn = 0; fn < 4; ++fn) {
            int d  = wn * 64 + fn * 16 + lr;       // row in vT
            int m0 = wm * 64 + fm * 16 + lq * 4;   // 4 consecutive m
            f32x4 a = acc2[fm * 4 + fn];
            unsigned short tmp[4] __attribute__((aligned(8)));
#pragma unroll
            for (int r = 0; r < 4; ++r) tmp[r] = f2b(2.0f * a[r]);
            *(uint2*)(smem + 65536 + d * 512 + ((m0 * 2) ^ ((d & 7) << 4))) = *(const uint2*)tmp;
        }
    __syncthreads();

    // ---- P6: acc += adj @ v  [K=256] (B-op from vT)
#pragma unroll
    for (int kk = 0; kk < 8; ++kk) {
        int kb = kk * 64 + lq * 16;
        bf16x8 afr[4], bfr[4];
#pragma unroll
        for (int fm = 0; fm < 4; ++fm) {
            int row = wm * 64 + fm * 16 + lr;
            afr[fm] = __builtin_bit_cast(bf16x8, *(const uint4*)(adj + row * N_ + kk * 32 + lq * 8));
        }
#pragma unroll
        for (int fn = 0; fn < 4; ++fn) {
            int d = wn * 64 + fn * 16 + lr;
            bfr[fn] = __builtin_bit_cast(bf16x8, *(const uint4*)(smem + 65536 + d * 512 + (kb ^ ((d & 7) << 4))));
        }
#pragma unroll
        for (int fm = 0; fm < 4; ++fm)
#pragma unroll
            for (int fn = 0; fn < 4; ++fn)
                accy[fm * 4 + fn] = __builtin_amdgcn_mfma_f32_16x16x32_bf16(afr[fm], bfr[fn], accy[fm * 4 + fn], 0, 0, 0);
    }

    // ---- P7: direct f32 global store (out is float32)
#pragma unroll
    for (int fm = 0; fm < 4; ++fm)
#pragma unroll
        for (int fn = 0; fn < 4; ++fn) {
            int col = wn * 64 + fn * 16 + lr;
            f32x4 a = accy[fm * 4 + fn];
#pragma unroll
            for (int r = 0; r < 4; ++r) {
                int row = wm * 64 + fm * 16 + lq * 4 + r;
                og[row * C_ + col] = a[r];
            }
        }
}

// ---------------------------------------------------------------------------
extern "C" void kernel_launch(void* const* d_in, const int* in_sizes, int n_in,
                              void* d_out, int out_size, void* d_ws, size_t ws_size,
                              hipStream_t stream)
{
    const float* timep = (const float*)d_in[0];
    const float* frep  = (const float*)d_in[1];
    const float* adjf  = (const float*)d_in[2];
    const float* lat   = (const float*)d_in[3];
    const float* sct   = (const float*)d_in[4];
    const float* scf   = (const float*)d_in[5];
    const float* Wt    = (const float*)d_in[6];
    const float* bt    = (const float*)d_in[7];
    const float* Wf    = (const float*)d_in[8];
    const float* bf    = (const float*)d_in[9];
    float* outp = (float*)d_out;

    float* fused_ws = (float*)d_ws;                                     // 2 MB
    unsigned short* wtp    = (unsigned short*)((char*)d_ws + 2097152);  // 192 KB
    unsigned short* adj_bs = (unsigned short*)((char*)d_ws + 2097152 + 196608); // 128 KB

    hipFuncSetAttribute((const void*)k_latent, hipFuncAttributeMaxDynamicSharedMemorySize, 141312);
    hipFuncSetAttribute((const void*)k_main,   hipFuncAttributeMaxDynamicSharedMemorySize, 133120);

    k_prep<<<640, 256, 0, stream>>>(Wt, Wf, adjf, wtp, adj_bs);
    k_latent<<<1024, 256, 141312, stream>>>(timep, frep, lat, fused_ws);
    k_main<<<dim3(1024, 2), 512, 133120, stream>>>(timep, frep, adj_bs, fused_ws,
                                                   sct, scf, wtp, bt, bf, outp);
}